// Round 15
// baseline (322.123 us; speedup 1.0000x reference)
//
#include <hip/hip_runtime.h>
#include <hip/hip_bf16.h>
#include <stdint.h>

typedef __attribute__((ext_vector_type(8))) short short8;
typedef __attribute__((ext_vector_type(4))) float f32x4;
typedef __attribute__((ext_vector_type(4))) unsigned short us4;

#define DIMC 768
#define NTOK 32768
#define NPB 4096
#define HEADS 8
#define DH 96

__device__ __forceinline__ ushort f2bf(float f) {
    union { float f; uint32_t u; } c; c.f = f;
    uint32_t u = c.u;
    u += 0x7fffu + ((u >> 16) & 1u);
    return (ushort)(u >> 16);
}
__device__ __forceinline__ float bf2f(ushort h) {
    union { uint32_t u; float f; } c; c.u = ((uint32_t)h) << 16;
    return c.f;
}

__device__ __forceinline__ void gload_lds16(const void* g, void* l) {
    __builtin_amdgcn_global_load_lds(
        (const __attribute__((address_space(1))) void*)g,
        (__attribute__((address_space(3))) void*)l, 16, 0, 0);
}

// =====================================================================
// 128x256-tile BK=32 GEMM core — FULL K=768.
// K-TILE LEDGER (audited): loop i=0..11, each iteration processes TWO
// BK=32 tiles (2i via buf0 in Ph1+Ph2, 2i+1 via buf1 in Ph3+Ph4).
// 12 iters x 2 tiles x 32 = K=768. Per tile: 4m x 4n = 16 MFMA.
// 8 waves (2Mx4N), each 64x64 output. LDS 48 KiB: A[2][128][32] +
// B[2][256][32] bf16 -> 3 blocks/CU (R12-measured shape: 10% faster than
// 256-sq at equal work, FETCH 36 MB @halfK, occupancy 34%, 0 conflicts).
// Schedule (race-audited for 24 tiles):
//  Ph1: read b0,a0[0-1]; STG A(2i+1)->buf1; BAR; lgkm0; MFMA; BAR
//  Ph2: read a0[2-3];    STG B(2i+2)->buf0; BAR; lgkm0; MFMA; vm; BAR
//       vm = (i<11) ? vmcnt(2) : vmcnt(0)
//       [drains B(2i+1):2 + A(2i+1):1 -> buf1 valid for Ph3; keeps
//        B(2i+2):2 in flight when present]
//  Ph3: read b1,a1[0-1]; STG A(2i+2)->buf0; BAR; lgkm0; MFMA; BAR
//  Ph4: read a1[2-3];    STG B(2i+3)->buf1; BAR; lgkm0; MFMA;
//       if (i<11) { vmcnt(2); BAR }   [drains B(2i+2)+A(2i+2) -> buf0
//       valid for next Ph1; keeps B(2i+3):2 in flight]
// Overwrite safety: each stage target's readers are drained by their
// phase's lgkm0, which precedes the barrier that separates reader from
// stage (verified per-phase R14->R15).
// Global row stride fixed 1536 B (= 768 ch * 2 B).
// =====================================================================
__device__ __forceinline__ void gemm128_core(
    const char* aglob, const char* bglob, char* lds, f32x4 (&acc)[4][4]) {
    const int tid = threadIdx.x;
    const int lane = tid & 63, wid = tid >> 6;
    const int wr = wid >> 2, wc = wid & 3;
    const int k8 = lane >> 4, l15 = lane & 15;

    const int LA = tid * 16;
    const int SA = LA ^ (((LA >> 9) & 1) << 5);
    const int sra = SA >> 6, sca = SA & 63;
    const int L0 = tid * 16, L1 = (512 + tid) * 16;
    const int S0 = L0 ^ (((L0 >> 9) & 1) << 5);
    const int S1 = L1 ^ (((L1 >> 9) & 1) << 5);
    const int sr0 = S0 >> 6, sc0 = S0 & 63;
    const int sr1 = S1 >> 6, sc1 = S1 & 63;

    int aoff[4], boff[4];
#pragma unroll
    for (int m = 0; m < 4; m++) {
        int row = wr * 64 + m * 16 + l15;          // 0..127
        int o = row * 64 + k8 * 16;
        aoff[m] = o ^ (((o >> 9) & 1) << 5);
    }
#pragma unroll
    for (int n = 0; n < 4; n++) {
        int row = wc * 64 + n * 16 + l15;          // 0..255
        int o = row * 64 + k8 * 16;
        boff[n] = o ^ (((o >> 9) & 1) << 5);
    }

#define QSTG_A(kt, c) do {                                    \
        const char* ak_ = aglob + (size_t)(kt) * 64;          \
        char* al_ = lds + (c) * 8192;                         \
        gload_lds16(ak_ + sra * 1536 + sca, al_ + LA);        \
    } while (0)
#define QSTG_B(kt, c) do {                                    \
        const char* bk_ = bglob + (size_t)(kt) * 64;          \
        char* bl_ = lds + 16384 + (c) * 16384;                \
        gload_lds16(bk_ + sr0 * 1536 + sc0, bl_ + L0);        \
        gload_lds16(bk_ + sr1 * 1536 + sc1, bl_ + L1);        \
    } while (0)
#define QMFMA8(mb)                                                                 \
    __builtin_amdgcn_s_setprio(1);                                                 \
    _Pragma("unroll")                                                              \
    for (int m_ = 0; m_ < 2; m_++)                                                 \
        _Pragma("unroll")                                                          \
        for (int n_ = 0; n_ < 4; n_++)                                             \
            acc[(mb) + m_][n_] = __builtin_amdgcn_mfma_f32_16x16x32_bf16(          \
                af[m_], bf[n_], acc[(mb) + m_][n_], 0, 0, 0);                      \
    __builtin_amdgcn_s_setprio(0);
#define BAR  asm volatile("s_barrier" ::: "memory")
#define LGKM0 do { asm volatile("s_waitcnt lgkmcnt(0)" ::: "memory"); \
                   __builtin_amdgcn_sched_barrier(0); } while (0)

    const char* a0 = lds;
    const char* a1 = lds + 8192;
    const char* b0 = lds + 16384;
    const char* b1 = lds + 32768;

    // prologue: B(0):2 + A(0):1 drained; B(1):2 in flight
    QSTG_B(0, 0); QSTG_A(0, 0); QSTG_B(1, 1);
    asm volatile("s_waitcnt vmcnt(2)" ::: "memory");
    BAR;

#pragma unroll 2
    for (int i = 0; i < 12; ++i) {
        short8 af[2], bf[4];
        // ---- Ph1: tile 2i (buf0), m0-1 ----
#pragma unroll
        for (int n = 0; n < 4; n++) bf[n] = *(const short8*)(b0 + boff[n]);
#pragma unroll
        for (int m = 0; m < 2; m++) af[m] = *(const short8*)(a0 + aoff[m]);
        QSTG_A(2 * i + 1, 1);                       // 2i+1 <= 23 always
        BAR;
        LGKM0;
        QMFMA8(0)
        BAR;
        // ---- Ph2: tile 2i (buf0), m2-3 ----
#pragma unroll
        for (int m = 0; m < 2; m++) af[m] = *(const short8*)(a0 + aoff[2 + m]);
        if (2 * i + 2 < 24) QSTG_B(2 * i + 2, 0);
        BAR;
        LGKM0;
        QMFMA8(2)
        if (i < 11) asm volatile("s_waitcnt vmcnt(2)" ::: "memory");
        else        asm volatile("s_waitcnt vmcnt(0)" ::: "memory");
        BAR;       // buf1 tile 2i+1 now valid block-wide
        // ---- Ph3: tile 2i+1 (buf1), m0-1 ----
#pragma unroll
        for (int n = 0; n < 4; n++) bf[n] = *(const short8*)(b1 + boff[n]);
#pragma unroll
        for (int m = 0; m < 2; m++) af[m] = *(const short8*)(a1 + aoff[m]);
        if (2 * i + 2 < 24) QSTG_A(2 * i + 2, 0);
        BAR;
        LGKM0;
        QMFMA8(0)
        BAR;
        // ---- Ph4: tile 2i+1 (buf1), m2-3 ----
#pragma unroll
        for (int m = 0; m < 2; m++) af[m] = *(const short8*)(a1 + aoff[2 + m]);
        if (2 * i + 3 < 24) QSTG_B(2 * i + 3, 1);
        BAR;
        LGKM0;
        QMFMA8(2)
        if (i < 11) {
            asm volatile("s_waitcnt vmcnt(2)" ::: "memory");
            BAR;   // buf0 tile 2i+2 now valid block-wide
        }
    }
#undef QSTG_A
#undef QSTG_B
#undef QMFMA8
#undef BAR
#undef LGKM0
}

// ---------------- fused prep: weight bf16 casts + LayerNorm cast -----------
__global__ __launch_bounds__(256) void prep_fused_kernel(
    const float* __restrict__ qw, const float* __restrict__ pw,
    ushort* __restrict__ qwb, ushort* __restrict__ pwb,
    const float* __restrict__ x, const float* __restrict__ g,
    const float* __restrict__ b, ushort* __restrict__ xb) {
    int bid = blockIdx.x;
    if (bid < 1728) {
        int i4 = (bid * 256 + threadIdx.x) * 4;
        if (i4 < 3 * DIMC * DIMC) {
            float4 w = *(const float4*)&qw[i4];
            us4 o;
            o[0] = f2bf(w.x); o[1] = f2bf(w.y); o[2] = f2bf(w.z); o[3] = f2bf(w.w);
            *(us4*)&qwb[i4] = o;
        }
        if (i4 < DIMC * DIMC) {
            float4 w = *(const float4*)&pw[i4];
            us4 o;
            o[0] = f2bf(w.x); o[1] = f2bf(w.y); o[2] = f2bf(w.z); o[3] = f2bf(w.w);
            *(us4*)&pwb[i4] = o;
        }
        return;
    }
    int t = (bid - 1728) * 4 + (threadIdx.x >> 6);
    int lane = threadIdx.x & 63;
    const float* xr = x + (size_t)t * DIMC;
    float4 v[3];
    float s = 0.f, s2 = 0.f;
#pragma unroll
    for (int u = 0; u < 3; u++) {
        v[u] = *(const float4*)&xr[u * 256 + lane * 4];
        s  += v[u].x + v[u].y + v[u].z + v[u].w;
        s2 += v[u].x * v[u].x + v[u].y * v[u].y + v[u].z * v[u].z + v[u].w * v[u].w;
    }
#pragma unroll
    for (int off = 32; off > 0; off >>= 1) {
        s  += __shfl_down(s, off);
        s2 += __shfl_down(s2, off);
    }
    s = __shfl(s, 0);
    s2 = __shfl(s2, 0);
    float mean = s * (1.0f / DIMC);
    float rstd = rsqrtf(s2 * (1.0f / DIMC) - mean * mean + 1e-5f);
    ushort* xo = xb + (size_t)t * DIMC;
#pragma unroll
    for (int u = 0; u < 3; u++) {
        float4 gv = *(const float4*)&g[u * 256 + lane * 4];
        float4 bv = *(const float4*)&b[u * 256 + lane * 4];
        us4 o;
        o[0] = f2bf((v[u].x - mean) * rstd * gv.x + bv.x);
        o[1] = f2bf((v[u].y - mean) * rstd * gv.y + bv.y);
        o[2] = f2bf((v[u].z - mean) * rstd * gv.z + bv.z);
        o[3] = f2bf((v[u].w - mean) * rstd * gv.w + bv.w);
        *(us4*)&xo[u * 256 + lane * 4] = o;
    }
}

// ---------------- QKV GEMM: 128x256 tile, full K=768 ----------------
__global__ __launch_bounds__(512) void gemm_qkv_kernel(
    const ushort* __restrict__ xb, const ushort* __restrict__ wb,
    ushort* __restrict__ qb, ushort* __restrict__ kb, ushort* __restrict__ vb) {
    __shared__ __align__(16) char lds[49152];
    int orig = blockIdx.x;                   // 0..2303
    int wg = (orig & 7) * 288 + (orig >> 3);
    int nt = wg % 9, mt = wg / 9;
    int m0 = mt * 128, n0 = nt * 256;
    f32x4 acc[4][4] = {};
    gemm128_core((const char*)(xb + (size_t)m0 * DIMC),
                 (const char*)(wb + (size_t)n0 * DIMC), lds, acc);

    const int tid = threadIdx.x;
    const int lane = tid & 63, wid = tid >> 6;
    const int wr = wid >> 2, wc = wid & 3;
    const int k8 = lane >> 4, l15 = lane & 15;
    int seg = n0 / DIMC;                     // 0=q, 1=k, 2=v (no straddle)
#pragma unroll
    for (int m8 = 0; m8 < 4; m8++) {
        int r0 = m0 + wr * 64 + m8 * 16 + k8 * 4;
        int b_ = r0 >> 12, nn = r0 & (NPB - 1);
#pragma unroll
        for (int n = 0; n < 4; n++) {
            int o = n0 + wc * 64 + n * 16 + l15;
            f32x4 a = acc[m8][n];
            if (seg == 2) {
                int oL = o - 2 * DIMC;
#pragma unroll
                for (int qq = 0; qq < 4; qq++)
                    vb[(size_t)(r0 + qq) * DIMC + oL] = f2bf(a[qq]);
            } else {
                int oL = o - seg * DIMC;
                int h = oL / DH, d = oL - h * DH;
                us4 pk;
#pragma unroll
                for (int qq = 0; qq < 4; qq++) pk[qq] = f2bf(a[qq]);
                *(us4*)((seg ? kb : qb) +
                        ((size_t)(b_ * HEADS + h) * DH + d) * NPB + nn) = pk;
            }
        }
    }
}

// ---------------- attn partial: S[ch][bh][96][96] (bf16) + sumsq partials --
__global__ __launch_bounds__(576) void attn_qk_kernel(
    const ushort* __restrict__ qb, const ushort* __restrict__ kb,
    ushort* __restrict__ S, float* __restrict__ S2) {
    int bh = blockIdx.x, ch = blockIdx.y;
    int tid = threadIdx.x, wid = tid >> 6, lane = tid & 63;
    int wr = wid / 3, wc = wid - wr * 3;
    int k8 = lane >> 4, l15 = lane & 15;
    const ushort* qrow = qb + (size_t)bh * DH * NPB + ch * 512;
    const ushort* krow = kb + (size_t)bh * DH * NPB + ch * 512;
    bool doq = (wc == 0), dok = (wr == 0);
    f32x4 acc[2][2] = {};
    float sq[2] = {0.f, 0.f}, sk[2] = {0.f, 0.f};
    for (int n = 0; n < 512; n += 32) {
        short8 a[2], b[2];
#pragma unroll
        for (int i = 0; i < 2; i++)
            a[i] = *(const short8*)&qrow[(size_t)(wr * 32 + i * 16 + l15) * NPB + n + k8 * 8];
#pragma unroll
        for (int j = 0; j < 2; j++)
            b[j] = *(const short8*)&krow[(size_t)(wc * 32 + j * 16 + l15) * NPB + n + k8 * 8];
        if (doq) {
#pragma unroll
            for (int i = 0; i < 2; i++)
#pragma unroll
                for (int u = 0; u < 8; u++) {
                    float f = bf2f((ushort)a[i][u]); sq[i] += f * f;
                }
        }
        if (dok) {
#pragma unroll
            for (int j = 0; j < 2; j++)
#pragma unroll
                for (int u = 0; u < 8; u++) {
                    float f = bf2f((ushort)b[j][u]); sk[j] += f * f;
                }
        }
#pragma unroll
        for (int i = 0; i < 2; i++)
#pragma unroll
            for (int j = 0; j < 2; j++)
                acc[i][j] = __builtin_amdgcn_mfma_f32_16x16x32_bf16(a[i], b[j], acc[i][j], 0, 0, 0);
    }
    float* S2o = S2 + ((size_t)ch * 64 + bh) * 192;
    if (doq) {
#pragma unroll
        for (int i = 0; i < 2; i++) {
            float v = sq[i];
            v += __shfl_xor(v, 16); v += __shfl_xor(v, 32);
            if (lane < 16) S2o[wr * 32 + i * 16 + l15] = v;
        }
    }
    if (dok) {
#pragma unroll
        for (int j = 0; j < 2; j++) {
            float v = sk[j];
            v += __shfl_xor(v, 16); v += __shfl_xor(v, 32);
            if (lane < 16) S2o[96 + wc * 32 + j * 16 + l15] = v;
        }
    }
    ushort* So = S + ((size_t)ch * 64 + bh) * (DH * DH);
#pragma unroll
    for (int i = 0; i < 2; i++)
#pragma unroll
        for (int j = 0; j < 2; j++) {
            int e = wc * 32 + j * 16 + l15;
#pragma unroll
            for (int qq = 0; qq < 4; qq++) {
                int d = wr * 32 + i * 16 + k8 * 4 + qq;
                So[d * DH + e] = f2bf(acc[i][j][qq]);
            }
        }
}

// ---------------- attn finish: chunk-reduce + softmax + W2 GEMM (fused) ----
__global__ __launch_bounds__(576) void attn_finish_kernel(
    const ushort* __restrict__ S, const float* __restrict__ S2,
    const float* __restrict__ temp, const ushort* __restrict__ pwb,
    ushort* __restrict__ W2) {
    int bh = blockIdx.x;
    int b_ = bh >> 3, h = bh & 7;
    int tid = threadIdx.x;
    __shared__ float rkv[96];
    __shared__ float red[96][6], red2[96][6];
    __shared__ ushort atl[96][104];   // [e][d], padded pitch
    int r = tid % 96, p = tid / 96;   // row d, col-group of 16
    if (tid < 96) {
        float sum = 0.f;
#pragma unroll 1
        for (int ch = 0; ch < 8; ch++)
            sum += S2[((size_t)ch * 64 + bh) * 192 + 96 + tid];
        rkv[tid] = 1.0f / fmaxf(sqrtf(sum), 1e-12f);
    }
    float sqd = 0.f;
#pragma unroll 1
    for (int ch = 0; ch < 8; ch++)
        sqd += S2[((size_t)ch * 64 + bh) * 192 + r];
    float rqd = 1.0f / fmaxf(sqrtf(sqd), 1e-12f);
    float v[16];
#pragma unroll
    for (int u = 0; u < 16; u++) v[u] = 0.f;
#pragma unroll 1
    for (int ch = 0; ch < 8; ch++) {
        const ushort* So = S + ((size_t)ch * 64 + bh) * (DH * DH) + r * DH + p * 16;
        short8 w0 = *(const short8*)So;
        short8 w1 = *(const short8*)(So + 8);
#pragma unroll
        for (int u = 0; u < 8; u++) {
            v[u] += bf2f((ushort)w0[u]);
            v[8 + u] += bf2f((ushort)w1[u]);
        }
    }
    __syncthreads();   // rkv ready
    float sd = rqd * temp[h];
#pragma unroll
    for (int u = 0; u < 16; u++) v[u] *= sd * rkv[p * 16 + u];
    float lm = v[0];
#pragma unroll
    for (int u = 1; u < 16; u++) lm = fmaxf(lm, v[u]);
    red[r][p] = lm;
    __syncthreads();
    float m = red[r][0];
#pragma unroll
    for (int u = 1; u < 6; u++) m = fmaxf(m, red[r][u]);
    float s = 0.f;
#pragma unroll
    for (int u = 0; u < 16; u++) { v[u] = __expf(v[u] - m); s += v[u]; }
    red2[r][p] = s;
    __syncthreads();
    float tot = red2[r][0];
#pragma unroll
    for (int u = 1; u < 6; u++) tot += red2[r][u];
    float inv = 1.0f / tot;
#pragma unroll
    for (int u = 0; u < 16; u++)
        atl[p * 16 + u][r] = f2bf(v[u] * inv);
    __syncthreads();
    // ---- Phase B: W2[b][o][h*96+e] = sum_d pw[o][h*96+d] * attn[d][e] ----
    int wid = tid >> 6, lane = tid & 63;
    if (wid < 8) {
        int k8 = lane >> 4, l15 = lane & 15;
        ushort* wo = W2 + (size_t)b_ * DIMC * DIMC + (size_t)h * DH;
#pragma unroll
        for (int pass = 0; pass < 2; pass++) {
            int o0 = wid * 96 + pass * 48;
            f32x4 acc[3][6] = {};
#pragma unroll
            for (int kk = 0; kk < DH; kk += 32) {
                short8 af[3], bf[6];
#pragma unroll
                for (int mm = 0; mm < 3; mm++)
                    af[mm] = *(const short8*)&pwb[(size_t)(o0 + mm * 16 + l15) * DIMC
                                                  + h * DH + kk + k8 * 8];
#pragma unroll
                for (int n = 0; n < 6; n++)
                    bf[n] = *(const short8*)&atl[n * 16 + l15][kk + k8 * 8];
#pragma unroll
                for (int mm = 0; mm < 3; mm++)
#pragma unroll
                    for (int n = 0; n < 6; n++)
                        acc[mm][n] = __builtin_amdgcn_mfma_f32_16x16x32_bf16(
                            af[mm], bf[n], acc[mm][n], 0, 0, 0);
            }
#pragma unroll
            for (int mm = 0; mm < 3; mm++) {
                int orow = o0 + mm * 16 + k8 * 4;
#pragma unroll
                for (int n = 0; n < 6; n++) {
                    int e = n * 16 + l15;
#pragma unroll
                    for (int qq = 0; qq < 4; qq++)
                        wo[(size_t)(orow + qq) * DIMC + e] = f2bf(acc[mm][n][qq]);
                }
            }
        }
    }
}

// ---------------- vproj: out = g1*(v·W2[b]^T + pb) + x  (128x256, full K) --
__global__ __launch_bounds__(512) void vproj_kernel(
    const ushort* __restrict__ vb, const ushort* __restrict__ W2,
    const float* __restrict__ pb, const float* __restrict__ g1,
    const float* __restrict__ x, float* __restrict__ out) {
    __shared__ __align__(16) char lds[49152];
    int orig = blockIdx.x;                   // 0..767
    int wg = (orig & 7) * 96 + (orig >> 3);
    int b_ = wg / 96, rem = wg % 96, mt = rem / 3, ntl = rem % 3;
    int tok0 = b_ * NPB + mt * 128, o0 = ntl * 256;
    f32x4 acc[4][4] = {};
    gemm128_core((const char*)(vb + (size_t)tok0 * DIMC),
                 (const char*)(W2 + (size_t)b_ * DIMC * DIMC + (size_t)o0 * DIMC),
                 lds, acc);

    const int tid = threadIdx.x;
    const int lane = tid & 63, wid = tid >> 6;
    const int wr = wid >> 2, wc = wid & 3;
    const int k8 = lane >> 4, l15 = lane & 15;
#pragma unroll
    for (int m8 = 0; m8 < 4; m8++) {
        int r0 = tok0 + wr * 64 + m8 * 16 + k8 * 4;
#pragma unroll
        for (int n = 0; n < 4; n++) {
            int o = o0 + wc * 64 + n * 16 + l15;
            float pbo = pb[o], g1o = g1[o];
            f32x4 a = acc[m8][n];
#pragma unroll
            for (int qq = 0; qq < 4; qq++) {
                size_t idx = (size_t)(r0 + qq) * DIMC + o;
                out[idx] = g1o * (a[qq] + pbo) + x[idx];
            }
        }
    }
}

extern "C" void kernel_launch(void* const* d_in, const int* in_sizes, int n_in,
                              void* d_out, int out_size, void* d_ws, size_t ws_size,
                              hipStream_t stream) {
    const float* x     = (const float*)d_in[0];
    const float* qkvw  = (const float*)d_in[1];
    const float* projw = (const float*)d_in[2];
    const float* projb = (const float*)d_in[3];
    const float* lng   = (const float*)d_in[4];
    const float* lnb   = (const float*)d_in[5];
    const float* temp  = (const float*)d_in[6];
    const float* g1    = (const float*)d_in[7];
    float* out = (float*)d_out;

    char* w = (char*)d_ws;
    ushort* qb    = (ushort*)(w + 0);            // 50,331,648  [B,H,dh,N]
    ushort* kb    = (ushort*)(w + 50331648);     // 50,331,648
    ushort* vb    = (ushort*)(w + 100663296);    // 50,331,648  [T, C] token-major
    ushort* qwb   = (ushort*)(w + 150994944);    // 3,538,944
    ushort* pwb   = (ushort*)(w + 154533888);    // 1,179,648
    float*  S2    = (float*)(w + 155713536);     // 393,216 sumsq partials
    ushort* W2    = qb;                          // 9,437,184 (aliases dead qb)
    ushort* xb    = (ushort*)d_out;              // LN output (dead before vproj)
    ushort* Sb    = (ushort*)((char*)d_out + 50331648);  // 9.4 MB bf16 partials

    hipLaunchKernelGGL(prep_fused_kernel, dim3(9920), dim3(256), 0, stream,
                       qkvw, projw, qwb, pwb, x, lng, lnb, xb);
    hipLaunchKernelGGL(gemm_qkv_kernel, dim3(2304), dim3(512), 0, stream,
                       xb, qwb, qb, kb, vb);
    hipLaunchKernelGGL(attn_qk_kernel, dim3(64, 8), dim3(576), 0, stream,
                       qb, kb, Sb, S2);
    hipLaunchKernelGGL(attn_finish_kernel, dim3(64), dim3(576), 0, stream,
                       Sb, S2, temp, pwb, W2);
    hipLaunchKernelGGL(vproj_kernel, dim3(768), dim3(512), 0, stream,
                       vb, W2, projb, g1, x, out);
}

// Round 16
// 309.478 us; speedup vs baseline: 1.0409x; 1.0409x over previous
//
#include <hip/hip_runtime.h>
#include <hip/hip_bf16.h>
#include <stdint.h>

typedef __attribute__((ext_vector_type(8))) short short8;
typedef __attribute__((ext_vector_type(4))) float f32x4;
typedef __attribute__((ext_vector_type(4))) unsigned short us4;

#define DIMC 768
#define NTOK 32768
#define NPB 4096
#define HEADS 8
#define DH 96

__device__ __forceinline__ ushort f2bf(float f) {
    union { float f; uint32_t u; } c; c.f = f;
    uint32_t u = c.u;
    u += 0x7fffu + ((u >> 16) & 1u);
    return (ushort)(u >> 16);
}
__device__ __forceinline__ float bf2f(ushort h) {
    union { uint32_t u; float f; } c; c.u = ((uint32_t)h) << 16;
    return c.f;
}

__device__ __forceinline__ void gload_lds16(const void* g, void* l) {
    __builtin_amdgcn_global_load_lds(
        (const __attribute__((address_space(1))) void*)g,
        (__attribute__((address_space(3))) void*)l, 16, 0, 0);
}

// =====================================================================
// 256x256-tile BK=32 GEMM core — FULL K=768 (24 tiles). R14-measured:
// qkv 150us, absmax 0.0078, FETCH 100 MB, 0 bank conflicts, 2 blocks/CU.
// Best measured shape for the schedule-bound qkv GEMM (lower B traffic).
// =====================================================================
__device__ __forceinline__ void gemm256_core(
    const char* aglob, const char* bglob, char* lds, f32x4 (&acc)[8][4]) {
    const int tid = threadIdx.x;
    const int lane = tid & 63, wid = tid >> 6;
    const int wr = wid >> 2, wc = wid & 3;
    const int k8 = lane >> 4, l15 = lane & 15;

    const int L0 = tid * 16, L1 = (512 + tid) * 16;
    const int S0 = L0 ^ (((L0 >> 9) & 1) << 5);
    const int S1 = L1 ^ (((L1 >> 9) & 1) << 5);
    const int sr0 = S0 >> 6, sc0 = S0 & 63;
    const int sr1 = S1 >> 6, sc1 = S1 & 63;

    int aoff[8], boff[4];
#pragma unroll
    for (int m = 0; m < 8; m++) {
        int row = wr * 128 + m * 16 + l15;
        int o = row * 64 + k8 * 16;
        aoff[m] = o ^ (((o >> 9) & 1) << 5);
    }
#pragma unroll
    for (int n = 0; n < 4; n++) {
        int row = wc * 64 + n * 16 + l15;
        int o = row * 64 + k8 * 16;
        boff[n] = o ^ (((o >> 9) & 1) << 5);
    }

#define STG_A(kt, c) do {                                     \
        const char* ak_ = aglob + (size_t)(kt) * 64;          \
        char* al_ = lds + (c) * 16384;                        \
        gload_lds16(ak_ + sr0 * 1536 + sc0, al_ + L0);        \
        gload_lds16(ak_ + sr1 * 1536 + sc1, al_ + L1);        \
    } while (0)
#define STG_B(kt, c) do {                                     \
        const char* bk_ = bglob + (size_t)(kt) * 64;          \
        char* bl_ = lds + 32768 + (c) * 16384;                \
        gload_lds16(bk_ + sr0 * 1536 + sc0, bl_ + L0);        \
        gload_lds16(bk_ + sr1 * 1536 + sc1, bl_ + L1);        \
    } while (0)
#define MFMA_PAIR(ma, mb)                                                          \
    __builtin_amdgcn_s_setprio(1);                                                 \
    _Pragma("unroll")                                                              \
    for (int n = 0; n < 4; n++)                                                    \
        acc[ma][n] = __builtin_amdgcn_mfma_f32_16x16x32_bf16(af[ma], bf[n], acc[ma][n], 0, 0, 0); \
    _Pragma("unroll")                                                              \
    for (int n = 0; n < 4; n++)                                                    \
        acc[mb][n] = __builtin_amdgcn_mfma_f32_16x16x32_bf16(af[mb], bf[n], acc[mb][n], 0, 0, 0); \
    __builtin_amdgcn_s_setprio(0);

    STG_A(0, 0); STG_B(0, 0); STG_B(1, 1);
    asm volatile("s_waitcnt vmcnt(2)" ::: "memory");
    asm volatile("s_barrier" ::: "memory");

#pragma unroll 2
    for (int t = 0; t < 24; ++t) {
        const int c = t & 1;
        const char* ap = lds + c * 16384;
        const char* bp = lds + 32768 + c * 16384;
        short8 af[8], bf[4];
        // ---- Ph1 ----
#pragma unroll
        for (int n = 0; n < 4; n++) bf[n] = *(const short8*)(bp + boff[n]);
#pragma unroll
        for (int m = 0; m < 4; m++) af[m] = *(const short8*)(ap + aoff[m]);
        if (t + 1 < 24) STG_A(t + 1, c ^ 1);
        asm volatile("s_barrier" ::: "memory");
        asm volatile("s_waitcnt lgkmcnt(2)" ::: "memory");
        __builtin_amdgcn_sched_barrier(0);
        MFMA_PAIR(0, 1)
        // ---- Ph2 ----
#pragma unroll
        for (int m = 4; m < 8; m++) af[m] = *(const short8*)(ap + aoff[m]);
        asm volatile("s_barrier" ::: "memory");
        asm volatile("s_waitcnt lgkmcnt(4)" ::: "memory");
        __builtin_amdgcn_sched_barrier(0);
        MFMA_PAIR(2, 3)
        // ---- Ph3 ----
        if (t + 2 < 24) STG_B(t + 2, c);
        asm volatile("s_barrier" ::: "memory");
        asm volatile("s_waitcnt lgkmcnt(2)" ::: "memory");
        __builtin_amdgcn_sched_barrier(0);
        MFMA_PAIR(4, 5)
        // ---- Ph4 ----
        if (t + 2 < 24) asm volatile("s_waitcnt vmcnt(2)" ::: "memory");
        else            asm volatile("s_waitcnt vmcnt(0)" ::: "memory");
        asm volatile("s_waitcnt lgkmcnt(0)" ::: "memory");
        __builtin_amdgcn_sched_barrier(0);
        asm volatile("s_barrier" ::: "memory");
        MFMA_PAIR(6, 7)
    }
#undef STG_A
#undef STG_B
#undef MFMA_PAIR
}

// =====================================================================
// 128x256-tile BK=32 GEMM core — FULL K=768. R15-measured, absmax 0.0078.
// 48 KiB LDS -> 3 blocks/CU. Best measured shape for the HBM/latency-
// bound vproj GEMM (occupancy wins over B-traffic there).
// =====================================================================
__device__ __forceinline__ void gemm128_core(
    const char* aglob, const char* bglob, char* lds, f32x4 (&acc)[4][4]) {
    const int tid = threadIdx.x;
    const int lane = tid & 63, wid = tid >> 6;
    const int wr = wid >> 2, wc = wid & 3;
    const int k8 = lane >> 4, l15 = lane & 15;

    const int LA = tid * 16;
    const int SA = LA ^ (((LA >> 9) & 1) << 5);
    const int sra = SA >> 6, sca = SA & 63;
    const int L0 = tid * 16, L1 = (512 + tid) * 16;
    const int S0 = L0 ^ (((L0 >> 9) & 1) << 5);
    const int S1 = L1 ^ (((L1 >> 9) & 1) << 5);
    const int sr0 = S0 >> 6, sc0 = S0 & 63;
    const int sr1 = S1 >> 6, sc1 = S1 & 63;

    int aoff[4], boff[4];
#pragma unroll
    for (int m = 0; m < 4; m++) {
        int row = wr * 64 + m * 16 + l15;          // 0..127
        int o = row * 64 + k8 * 16;
        aoff[m] = o ^ (((o >> 9) & 1) << 5);
    }
#pragma unroll
    for (int n = 0; n < 4; n++) {
        int row = wc * 64 + n * 16 + l15;          // 0..255
        int o = row * 64 + k8 * 16;
        boff[n] = o ^ (((o >> 9) & 1) << 5);
    }

#define QSTG_A(kt, c) do {                                    \
        const char* ak_ = aglob + (size_t)(kt) * 64;          \
        char* al_ = lds + (c) * 8192;                         \
        gload_lds16(ak_ + sra * 1536 + sca, al_ + LA);        \
    } while (0)
#define QSTG_B(kt, c) do {                                    \
        const char* bk_ = bglob + (size_t)(kt) * 64;          \
        char* bl_ = lds + 16384 + (c) * 16384;                \
        gload_lds16(bk_ + sr0 * 1536 + sc0, bl_ + L0);        \
        gload_lds16(bk_ + sr1 * 1536 + sc1, bl_ + L1);        \
    } while (0)
#define QMFMA8(mb)                                                                 \
    __builtin_amdgcn_s_setprio(1);                                                 \
    _Pragma("unroll")                                                              \
    for (int m_ = 0; m_ < 2; m_++)                                                 \
        _Pragma("unroll")                                                          \
        for (int n_ = 0; n_ < 4; n_++)                                             \
            acc[(mb) + m_][n_] = __builtin_amdgcn_mfma_f32_16x16x32_bf16(          \
                af[m_], bf[n_], acc[(mb) + m_][n_], 0, 0, 0);                      \
    __builtin_amdgcn_s_setprio(0);
#define BAR  asm volatile("s_barrier" ::: "memory")
#define LGKM0 do { asm volatile("s_waitcnt lgkmcnt(0)" ::: "memory"); \
                   __builtin_amdgcn_sched_barrier(0); } while (0)

    const char* a0 = lds;
    const char* a1 = lds + 8192;
    const char* b0 = lds + 16384;
    const char* b1 = lds + 32768;

    QSTG_B(0, 0); QSTG_A(0, 0); QSTG_B(1, 1);
    asm volatile("s_waitcnt vmcnt(2)" ::: "memory");
    BAR;

#pragma unroll 2
    for (int i = 0; i < 12; ++i) {
        short8 af[2], bf[4];
        // ---- Ph1: tile 2i (buf0), m0-1 ----
#pragma unroll
        for (int n = 0; n < 4; n++) bf[n] = *(const short8*)(b0 + boff[n]);
#pragma unroll
        for (int m = 0; m < 2; m++) af[m] = *(const short8*)(a0 + aoff[m]);
        QSTG_A(2 * i + 1, 1);
        BAR;
        LGKM0;
        QMFMA8(0)
        BAR;
        // ---- Ph2: tile 2i (buf0), m2-3 ----
#pragma unroll
        for (int m = 0; m < 2; m++) af[m] = *(const short8*)(a0 + aoff[2 + m]);
        if (2 * i + 2 < 24) QSTG_B(2 * i + 2, 0);
        BAR;
        LGKM0;
        QMFMA8(2)
        if (i < 11) asm volatile("s_waitcnt vmcnt(2)" ::: "memory");
        else        asm volatile("s_waitcnt vmcnt(0)" ::: "memory");
        BAR;
        // ---- Ph3: tile 2i+1 (buf1), m0-1 ----
#pragma unroll
        for (int n = 0; n < 4; n++) bf[n] = *(const short8*)(b1 + boff[n]);
#pragma unroll
        for (int m = 0; m < 2; m++) af[m] = *(const short8*)(a1 + aoff[m]);
        if (2 * i + 2 < 24) QSTG_A(2 * i + 2, 0);
        BAR;
        LGKM0;
        QMFMA8(0)
        BAR;
        // ---- Ph4: tile 2i+1 (buf1), m2-3 ----
#pragma unroll
        for (int m = 0; m < 2; m++) af[m] = *(const short8*)(a1 + aoff[2 + m]);
        if (2 * i + 3 < 24) QSTG_B(2 * i + 3, 1);
        BAR;
        LGKM0;
        QMFMA8(2)
        if (i < 11) {
            asm volatile("s_waitcnt vmcnt(2)" ::: "memory");
            BAR;
        }
    }
#undef QSTG_A
#undef QSTG_B
#undef QMFMA8
#undef BAR
#undef LGKM0
}

// ---------------- fused prep: weight bf16 casts + LayerNorm cast -----------
__global__ __launch_bounds__(256) void prep_fused_kernel(
    const float* __restrict__ qw, const float* __restrict__ pw,
    ushort* __restrict__ qwb, ushort* __restrict__ pwb,
    const float* __restrict__ x, const float* __restrict__ g,
    const float* __restrict__ b, ushort* __restrict__ xb) {
    int bid = blockIdx.x;
    if (bid < 1728) {
        int i4 = (bid * 256 + threadIdx.x) * 4;
        if (i4 < 3 * DIMC * DIMC) {
            float4 w = *(const float4*)&qw[i4];
            us4 o;
            o[0] = f2bf(w.x); o[1] = f2bf(w.y); o[2] = f2bf(w.z); o[3] = f2bf(w.w);
            *(us4*)&qwb[i4] = o;
        }
        if (i4 < DIMC * DIMC) {
            float4 w = *(const float4*)&pw[i4];
            us4 o;
            o[0] = f2bf(w.x); o[1] = f2bf(w.y); o[2] = f2bf(w.z); o[3] = f2bf(w.w);
            *(us4*)&pwb[i4] = o;
        }
        return;
    }
    int t = (bid - 1728) * 4 + (threadIdx.x >> 6);
    int lane = threadIdx.x & 63;
    const float* xr = x + (size_t)t * DIMC;
    float4 v[3];
    float s = 0.f, s2 = 0.f;
#pragma unroll
    for (int u = 0; u < 3; u++) {
        v[u] = *(const float4*)&xr[u * 256 + lane * 4];
        s  += v[u].x + v[u].y + v[u].z + v[u].w;
        s2 += v[u].x * v[u].x + v[u].y * v[u].y + v[u].z * v[u].z + v[u].w * v[u].w;
    }
#pragma unroll
    for (int off = 32; off > 0; off >>= 1) {
        s  += __shfl_down(s, off);
        s2 += __shfl_down(s2, off);
    }
    s = __shfl(s, 0);
    s2 = __shfl(s2, 0);
    float mean = s * (1.0f / DIMC);
    float rstd = rsqrtf(s2 * (1.0f / DIMC) - mean * mean + 1e-5f);
    ushort* xo = xb + (size_t)t * DIMC;
#pragma unroll
    for (int u = 0; u < 3; u++) {
        float4 gv = *(const float4*)&g[u * 256 + lane * 4];
        float4 bv = *(const float4*)&b[u * 256 + lane * 4];
        us4 o;
        o[0] = f2bf((v[u].x - mean) * rstd * gv.x + bv.x);
        o[1] = f2bf((v[u].y - mean) * rstd * gv.y + bv.y);
        o[2] = f2bf((v[u].z - mean) * rstd * gv.z + bv.z);
        o[3] = f2bf((v[u].w - mean) * rstd * gv.w + bv.w);
        *(us4*)&xo[u * 256 + lane * 4] = o;
    }
}

// ---------------- QKV GEMM: 256x256 full-K (measured-best for qkv) ---------
__global__ __launch_bounds__(512) void gemm_qkv_kernel(
    const ushort* __restrict__ xb, const ushort* __restrict__ wb,
    ushort* __restrict__ qb, ushort* __restrict__ kb, ushort* __restrict__ vb) {
    __shared__ __align__(16) char lds[65536];
    int orig = blockIdx.x;                   // 0..1151
    int wg = (orig & 7) * 144 + (orig >> 3);
    int nt = wg % 9, mt = wg / 9;
    int m0 = mt * 256, n0 = nt * 256;
    f32x4 acc[8][4] = {};
    gemm256_core((const char*)(xb + (size_t)m0 * DIMC),
                 (const char*)(wb + (size_t)n0 * DIMC), lds, acc);

    int tid = threadIdx.x, lane = tid & 63, wid = tid >> 6;
    int wr = wid >> 2, wc = wid & 3;
    int k8 = lane >> 4, l15 = lane & 15;
    int seg = n0 / DIMC;                     // 0=q, 1=k, 2=v (no straddle)
#pragma unroll
    for (int m8 = 0; m8 < 8; m8++) {
        int r0 = m0 + wr * 128 + m8 * 16 + k8 * 4;
        int b_ = r0 >> 12, nn = r0 & (NPB - 1);
#pragma unroll
        for (int n = 0; n < 4; n++) {
            int o = n0 + wc * 64 + n * 16 + l15;
            f32x4 a = acc[m8][n];
            if (seg == 2) {
                int oL = o - 2 * DIMC;
#pragma unroll
                for (int qq = 0; qq < 4; qq++)
                    vb[(size_t)(r0 + qq) * DIMC + oL] = f2bf(a[qq]);
            } else {
                int oL = o - seg * DIMC;
                int h = oL / DH, d = oL - h * DH;
                us4 pk;
#pragma unroll
                for (int qq = 0; qq < 4; qq++) pk[qq] = f2bf(a[qq]);
                *(us4*)((seg ? kb : qb) +
                        ((size_t)(b_ * HEADS + h) * DH + d) * NPB + nn) = pk;
            }
        }
    }
}

// ---------------- attn partial: S[ch][bh][96][96] (bf16) + sumsq partials --
__global__ __launch_bounds__(576) void attn_qk_kernel(
    const ushort* __restrict__ qb, const ushort* __restrict__ kb,
    ushort* __restrict__ S, float* __restrict__ S2) {
    int bh = blockIdx.x, ch = blockIdx.y;
    int tid = threadIdx.x, wid = tid >> 6, lane = tid & 63;
    int wr = wid / 3, wc = wid - wr * 3;
    int k8 = lane >> 4, l15 = lane & 15;
    const ushort* qrow = qb + (size_t)bh * DH * NPB + ch * 512;
    const ushort* krow = kb + (size_t)bh * DH * NPB + ch * 512;
    bool doq = (wc == 0), dok = (wr == 0);
    f32x4 acc[2][2] = {};
    float sq[2] = {0.f, 0.f}, sk[2] = {0.f, 0.f};
    for (int n = 0; n < 512; n += 32) {
        short8 a[2], b[2];
#pragma unroll
        for (int i = 0; i < 2; i++)
            a[i] = *(const short8*)&qrow[(size_t)(wr * 32 + i * 16 + l15) * NPB + n + k8 * 8];
#pragma unroll
        for (int j = 0; j < 2; j++)
            b[j] = *(const short8*)&krow[(size_t)(wc * 32 + j * 16 + l15) * NPB + n + k8 * 8];
        if (doq) {
#pragma unroll
            for (int i = 0; i < 2; i++)
#pragma unroll
                for (int u = 0; u < 8; u++) {
                    float f = bf2f((ushort)a[i][u]); sq[i] += f * f;
                }
        }
        if (dok) {
#pragma unroll
            for (int j = 0; j < 2; j++)
#pragma unroll
                for (int u = 0; u < 8; u++) {
                    float f = bf2f((ushort)b[j][u]); sk[j] += f * f;
                }
        }
#pragma unroll
        for (int i = 0; i < 2; i++)
#pragma unroll
            for (int j = 0; j < 2; j++)
                acc[i][j] = __builtin_amdgcn_mfma_f32_16x16x32_bf16(a[i], b[j], acc[i][j], 0, 0, 0);
    }
    float* S2o = S2 + ((size_t)ch * 64 + bh) * 192;
    if (doq) {
#pragma unroll
        for (int i = 0; i < 2; i++) {
            float v = sq[i];
            v += __shfl_xor(v, 16); v += __shfl_xor(v, 32);
            if (lane < 16) S2o[wr * 32 + i * 16 + l15] = v;
        }
    }
    if (dok) {
#pragma unroll
        for (int j = 0; j < 2; j++) {
            float v = sk[j];
            v += __shfl_xor(v, 16); v += __shfl_xor(v, 32);
            if (lane < 16) S2o[96 + wc * 32 + j * 16 + l15] = v;
        }
    }
    ushort* So = S + ((size_t)ch * 64 + bh) * (DH * DH);
#pragma unroll
    for (int i = 0; i < 2; i++)
#pragma unroll
        for (int j = 0; j < 2; j++) {
            int e = wc * 32 + j * 16 + l15;
#pragma unroll
            for (int qq = 0; qq < 4; qq++) {
                int d = wr * 32 + i * 16 + k8 * 4 + qq;
                So[d * DH + e] = f2bf(acc[i][j][qq]);
            }
        }
}

// ---------------- attn finish: chunk-reduce + softmax + W2 GEMM (fused) ----
__global__ __launch_bounds__(576) void attn_finish_kernel(
    const ushort* __restrict__ S, const float* __restrict__ S2,
    const float* __restrict__ temp, const ushort* __restrict__ pwb,
    ushort* __restrict__ W2) {
    int bh = blockIdx.x;
    int b_ = bh >> 3, h = bh & 7;
    int tid = threadIdx.x;
    __shared__ float rkv[96];
    __shared__ float red[96][6], red2[96][6];
    __shared__ ushort atl[96][104];   // [e][d], padded pitch
    int r = tid % 96, p = tid / 96;   // row d, col-group of 16
    if (tid < 96) {
        float sum = 0.f;
#pragma unroll 1
        for (int ch = 0; ch < 8; ch++)
            sum += S2[((size_t)ch * 64 + bh) * 192 + 96 + tid];
        rkv[tid] = 1.0f / fmaxf(sqrtf(sum), 1e-12f);
    }
    float sqd = 0.f;
#pragma unroll 1
    for (int ch = 0; ch < 8; ch++)
        sqd += S2[((size_t)ch * 64 + bh) * 192 + r];
    float rqd = 1.0f / fmaxf(sqrtf(sqd), 1e-12f);
    float v[16];
#pragma unroll
    for (int u = 0; u < 16; u++) v[u] = 0.f;
#pragma unroll 1
    for (int ch = 0; ch < 8; ch++) {
        const ushort* So = S + ((size_t)ch * 64 + bh) * (DH * DH) + r * DH + p * 16;
        short8 w0 = *(const short8*)So;
        short8 w1 = *(const short8*)(So + 8);
#pragma unroll
        for (int u = 0; u < 8; u++) {
            v[u] += bf2f((ushort)w0[u]);
            v[8 + u] += bf2f((ushort)w1[u]);
        }
    }
    __syncthreads();   // rkv ready
    float sd = rqd * temp[h];
#pragma unroll
    for (int u = 0; u < 16; u++) v[u] *= sd * rkv[p * 16 + u];
    float lm = v[0];
#pragma unroll
    for (int u = 1; u < 16; u++) lm = fmaxf(lm, v[u]);
    red[r][p] = lm;
    __syncthreads();
    float m = red[r][0];
#pragma unroll
    for (int u = 1; u < 6; u++) m = fmaxf(m, red[r][u]);
    float s = 0.f;
#pragma unroll
    for (int u = 0; u < 16; u++) { v[u] = __expf(v[u] - m); s += v[u]; }
    red2[r][p] = s;
    __syncthreads();
    float tot = red2[r][0];
#pragma unroll
    for (int u = 1; u < 6; u++) tot += red2[r][u];
    float inv = 1.0f / tot;
#pragma unroll
    for (int u = 0; u < 16; u++)
        atl[p * 16 + u][r] = f2bf(v[u] * inv);
    __syncthreads();
    // ---- Phase B: W2[b][o][h*96+e] = sum_d pw[o][h*96+d] * attn[d][e] ----
    int wid = tid >> 6, lane = tid & 63;
    if (wid < 8) {
        int k8 = lane >> 4, l15 = lane & 15;
        ushort* wo = W2 + (size_t)b_ * DIMC * DIMC + (size_t)h * DH;
#pragma unroll
        for (int pass = 0; pass < 2; pass++) {
            int o0 = wid * 96 + pass * 48;
            f32x4 acc[3][6] = {};
#pragma unroll
            for (int kk = 0; kk < DH; kk += 32) {
                short8 af[3], bf[6];
#pragma unroll
                for (int mm = 0; mm < 3; mm++)
                    af[mm] = *(const short8*)&pwb[(size_t)(o0 + mm * 16 + l15) * DIMC
                                                  + h * DH + kk + k8 * 8];
#pragma unroll
                for (int n = 0; n < 6; n++)
                    bf[n] = *(const short8*)&atl[n * 16 + l15][kk + k8 * 8];
#pragma unroll
                for (int mm = 0; mm < 3; mm++)
#pragma unroll
                    for (int n = 0; n < 6; n++)
                        acc[mm][n] = __builtin_amdgcn_mfma_f32_16x16x32_bf16(
                            af[mm], bf[n], acc[mm][n], 0, 0, 0);
            }
#pragma unroll
            for (int mm = 0; mm < 3; mm++) {
                int orow = o0 + mm * 16 + k8 * 4;
#pragma unroll
                for (int n = 0; n < 6; n++) {
                    int e = n * 16 + l15;
#pragma unroll
                    for (int qq = 0; qq < 4; qq++)
                        wo[(size_t)(orow + qq) * DIMC + e] = f2bf(acc[mm][n][qq]);
                }
            }
        }
    }
}

// ---------------- vproj: out = g1*(v·W2[b]^T + pb) + x  (128x256, full K) --
__global__ __launch_bounds__(512) void vproj_kernel(
    const ushort* __restrict__ vb, const ushort* __restrict__ W2,
    const float* __restrict__ pb, const float* __restrict__ g1,
    const float* __restrict__ x, float* __restrict__ out) {
    __shared__ __align__(16) char lds[49152];
    int orig = blockIdx.x;                   // 0..767
    int wg = (orig & 7) * 96 + (orig >> 3);
    int b_ = wg / 96, rem = wg % 96, mt = rem / 3, ntl = rem % 3;
    int tok0 = b_ * NPB + mt * 128, o0 = ntl * 256;
    f32x4 acc[4][4] = {};
    gemm128_core((const char*)(vb + (size_t)tok0 * DIMC),
                 (const char*)(W2 + (size_t)b_ * DIMC * DIMC + (size_t)o0 * DIMC),
                 lds, acc);

    const int tid = threadIdx.x;
    const int lane = tid & 63, wid = tid >> 6;
    const int wr = wid >> 2, wc = wid & 3;
    const int k8 = lane >> 4, l15 = lane & 15;
#pragma unroll
    for (int m8 = 0; m8 < 4; m8++) {
        int r0 = tok0 + wr * 64 + m8 * 16 + k8 * 4;
#pragma unroll
        for (int n = 0; n < 4; n++) {
            int o = o0 + wc * 64 + n * 16 + l15;
            float pbo = pb[o], g1o = g1[o];
            f32x4 a = acc[m8][n];
#pragma unroll
            for (int qq = 0; qq < 4; qq++) {
                size_t idx = (size_t)(r0 + qq) * DIMC + o;
                out[idx] = g1o * (a[qq] + pbo) + x[idx];
            }
        }
    }
}

extern "C" void kernel_launch(void* const* d_in, const int* in_sizes, int n_in,
                              void* d_out, int out_size, void* d_ws, size_t ws_size,
                              hipStream_t stream) {
    const float* x     = (const float*)d_in[0];
    const float* qkvw  = (const float*)d_in[1];
    const float* projw = (const float*)d_in[2];
    const float* projb = (const float*)d_in[3];
    const float* lng   = (const float*)d_in[4];
    const float* lnb   = (const float*)d_in[5];
    const float* temp  = (const float*)d_in[6];
    const float* g1    = (const float*)d_in[7];
    float* out = (float*)d_out;

    char* w = (char*)d_ws;
    ushort* qb    = (ushort*)(w + 0);            // 50,331,648  [B,H,dh,N]
    ushort* kb    = (ushort*)(w + 50331648);     // 50,331,648
    ushort* vb    = (ushort*)(w + 100663296);    // 50,331,648  [T, C] token-major
    ushort* qwb   = (ushort*)(w + 150994944);    // 3,538,944
    ushort* pwb   = (ushort*)(w + 154533888);    // 1,179,648
    float*  S2    = (float*)(w + 155713536);     // 393,216 sumsq partials
    ushort* W2    = qb;                          // 9,437,184 (aliases dead qb)
    ushort* xb    = (ushort*)d_out;              // LN output (dead before vproj)
    ushort* Sb    = (ushort*)((char*)d_out + 50331648);  // 9.4 MB bf16 partials

    hipLaunchKernelGGL(prep_fused_kernel, dim3(9920), dim3(256), 0, stream,
                       qkvw, projw, qwb, pwb, x, lng, lnb, xb);
    hipLaunchKernelGGL(gemm_qkv_kernel, dim3(1152), dim3(512), 0, stream,
                       xb, qwb, qb, kb, vb);
    hipLaunchKernelGGL(attn_qk_kernel, dim3(64, 8), dim3(576), 0, stream,
                       qb, kb, Sb, S2);
    hipLaunchKernelGGL(attn_finish_kernel, dim3(64), dim3(576), 0, stream,
                       Sb, S2, temp, pwb, W2);
    hipLaunchKernelGGL(vproj_kernel, dim3(768), dim3(512), 0, stream,
                       vb, W2, projb, g1, x, out);
}